// Round 7
// baseline (2230.106 us; speedup 1.0000x reference)
//
#include <hip/hip_runtime.h>
#include <cstddef>
#include <type_traits>

#define T_STEPS 512
#define BATCH   64
#define EDIM    512
#define HDIM    512
#define ODIM    512

#define W_ELEMS  (32 * 4 * 64 * 8)  // W kt 0..3: 65536 elems = 131072 B
#define HB_ELEMS (16 * 512)         // one h buffer: 8192 elems = 16384 B

typedef __bf16 bf16;
typedef __bf16 bf16x4 __attribute__((ext_vector_type(4)));
typedef __bf16 bf16x8 __attribute__((ext_vector_type(8)));
typedef float  f32x4  __attribute__((ext_vector_type(4)));

// LDS-only barrier: does NOT drain vmcnt, so in-flight global loads/stores
// (A prefetch, Hbf stores) ride across it. rule-18 fence: sched_barrier after.
__device__ __forceinline__ void barrier_lds() {
  asm volatile("s_waitcnt lgkmcnt(0)\n\ts_barrier" ::: "memory");
  __builtin_amdgcn_sched_barrier(0);
}

// ---------------------------------------------------------------------------
// MFMA GEMM (r6 proven, coalesced staging): C[r,n] = sum_k X[r,k]*W[n,kw0+k]
// + b[n]. 128x128 tile, BK=32, 4 waves. REMAP (proven): rows b*T+t -> t*B+b.
// ---------------------------------------------------------------------------
template <typename XT, bool REMAP>
__global__ __launch_bounds__(256) void gemm_mfma_kernel(
    const XT* __restrict__ X, int ldx,
    const float* __restrict__ W, int ldw, int kw0,
    const float* __restrict__ bias,
    float* __restrict__ C, int ldc, int K)
{
  __shared__ __align__(16) bf16 Asm[8 * 64 * 8];
  __shared__ __align__(16) bf16 Bsm[8 * 64 * 8];

  const int tid  = threadIdx.x;
  const int row0 = blockIdx.x * 128;
  const int col0 = blockIdx.y * 128;
  const int w    = tid >> 6, lane = tid & 63;
  const int q    = lane >> 4, nl = lane & 15;
  const int wm   = w >> 1, wn = w & 1;

  const int srow = tid >> 2;        // 0..63, + rep*64
  const int sq   = tid & 3;         // k-chunk: c0 = sq*8
  f32x4 acc[4][4] = {};

  for (int k0 = 0; k0 < K; k0 += 32) {
#pragma unroll
    for (int rep = 0; rep < 2; ++rep) {
      int rl = srow + rep * 64;                 // row_local 0..127
      int mt = rl >> 4, snl = rl & 15;
      bf16x8 v;
      const XT* src = X + (size_t)(row0 + rl) * ldx + k0 + sq * 8;
      if constexpr (std::is_same_v<XT, float>) {
        f32x4 a0 = *(const f32x4*)src;
        f32x4 a1 = *(const f32x4*)(src + 4);
#pragma unroll
        for (int u = 0; u < 4; ++u) { v[u] = (bf16)a0[u]; v[u + 4] = (bf16)a1[u]; }
      } else {
        v = *(const bf16x8*)src;
      }
      *(bf16x8*)&Asm[(size_t)((mt * 4 + sq) * 16 + snl) * 8] = v;
    }
#pragma unroll
    for (int rep = 0; rep < 2; ++rep) {
      int rl = srow + rep * 64;
      int nt = rl >> 4, snl = rl & 15;
      const float* src = W + (size_t)(col0 + rl) * ldw + kw0 + k0 + sq * 8;
      f32x4 b0 = *(const f32x4*)src;
      f32x4 b1 = *(const f32x4*)(src + 4);
      bf16x8 v;
#pragma unroll
      for (int u = 0; u < 4; ++u) { v[u] = (bf16)b0[u]; v[u + 4] = (bf16)b1[u]; }
      *(bf16x8*)&Bsm[(size_t)((nt * 4 + sq) * 16 + snl) * 8] = v;
    }
    __syncthreads();

    bf16x8 a[4], b[4];
#pragma unroll
    for (int i = 0; i < 4; ++i)
      a[i] = *(bf16x8*)&Asm[(size_t)((wm * 4 + i) * 64 + lane) * 8];
#pragma unroll
    for (int j = 0; j < 4; ++j)
      b[j] = *(bf16x8*)&Bsm[(size_t)((wn * 4 + j) * 64 + lane) * 8];
#pragma unroll
    for (int i = 0; i < 4; ++i)
#pragma unroll
      for (int j = 0; j < 4; ++j)
        acc[i][j] = __builtin_amdgcn_mfma_f32_16x16x32_bf16(a[i], b[j], acc[i][j], 0, 0, 0);
    __syncthreads();
  }

#pragma unroll
  for (int i = 0; i < 4; ++i)
#pragma unroll
    for (int j = 0; j < 4; ++j) {
      int colg = col0 + wn * 64 + j * 16 + nl;
#pragma unroll
      for (int r = 0; r < 4; ++r) {
        size_t rowg = (size_t)(row0 + wm * 64 + i * 16 + q * 4 + r);
        size_t crow = REMAP ? (((rowg & (T_STEPS - 1)) << 6) | (rowg >> 9)) : rowg;
        C[crow * ldc + colg] = acc[i][j][r] + bias[colg];
      }
    }
}

// ---------------------------------------------------------------------------
// Scan, round-7: r6 structure (proven 1174 us) with the K-loop restructured
// for explicit ILP. r6 model: step = 2483 (MFMA) + 3100 (LDS) cyc, ~ZERO
// overlap because each ds_read was issued right before its dependent MFMA.
// New: 4 groups; each group BATCHES 8 independent ds_read_b128 (4 af + 4 wb
// for one LDS-kt) into named temps, then a 16-MFMA burst (4 LDS-path +
// 12 reg-path, kts {g, 3g+4, 3g+5, 3g+6}). Group g+1's loads are independent
// of group g's MFMAs -> scheduler can issue them under the MFMA shadow.
// s_setprio(1) around MFMA bursts (T5: group structure creates wave role
// diversity, the regime where setprio pays).
// Temps +32 VGPR; 2 waves/SIMD cap is 256 (r4 lesson) -> safe.
// ---------------------------------------------------------------------------
template <int DBUF>
__global__ __launch_bounds__(512, 2) void scan_kernel(
    const float* __restrict__ A,     // [T, B, H] fp32 (t-major, REMAP GEMM)
    const float* __restrict__ W1,    // [H, E+H] fp32
    bf16* __restrict__ Hbf)          // [B, T, H] bf16
{
  extern __shared__ __align__(16) bf16 smem[];
  bf16* Wlds = smem;                       // [tg(32)][kt(4)][lane(64)][8]
  bf16* hb0  = smem + W_ELEMS;             // [16][512] swizzled
  bf16* hb1  = DBUF ? (hb0 + HB_ELEMS) : hb0;

  const int tid  = threadIdx.x;
  const int c    = blockIdx.x;
  const int w    = tid >> 6, lane = tid & 63;
  const int q    = lane >> 4, nl = lane & 15;
  const int rb0  = c * 16;
  const int n0   = w * 64;
  const int sw   = (nl & 7) << 3;          // elem-granularity row swizzle

  // ---- one-time: W kt 0..3, all 32 n-tiles -> LDS ------------------------
  for (int idx = tid; idx < 32 * 4 * 64; idx += 512) {
    int l  = idx & 63;
    int kt = (idx >> 6) & 3;
    int tg = idx >> 8;
    int n  = tg * 16 + (l & 15);
    int k  = kt * 32 + (l >> 4) * 8;
    const float* src = W1 + (size_t)n * (EDIM + HDIM) + EDIM + k;
    bf16x8 v;
#pragma unroll
    for (int u = 0; u < 8; ++u) v[u] = (bf16)src[u];
    *(bf16x8*)&Wlds[(size_t)idx * 8] = v;
  }

  // ---- one-time: W kt 4..15 for this wave's 4 tiles -> 192 VGPRs ---------
  bf16x8 Wreg[4][12];
#pragma unroll
  for (int i = 0; i < 4; ++i) {
    int n = n0 + i * 16 + nl;
    const float* wrow = W1 + (size_t)n * (EDIM + HDIM) + EDIM;
#pragma unroll
    for (int kt2 = 0; kt2 < 12; ++kt2) {
      const float* src = wrow + (kt2 + 4) * 32 + q * 8;
      bf16x8 v;
#pragma unroll
      for (int u = 0; u < 8; ++u) v[u] = (bf16)src[u];
      Wreg[i][kt2] = v;
    }
  }
  __syncthreads();

  // ---- prefetch A_0 (4x f32x4; t-major A; proven mapping) ----------------
  f32x4 An[4];
  {
    const float* ap = A + (size_t)(rb0 + nl) * HDIM + n0 + q * 4;
    An[0] = *(const f32x4*)(ap);
    An[1] = *(const f32x4*)(ap + 16);
    An[2] = *(const f32x4*)(ap + 32);
    An[3] = *(const f32x4*)(ap + 48);
  }

  f32x4 acc[4];

  for (int t = 0; t < T_STEPS; ++t) {
    bf16* hr = (t & 1) ? hb1 : hb0;
    bf16* hw = (t & 1) ? hb0 : hb1;

    // ---- acc init from prefetched A_t; issue A_{t+1} prefetch ------------
#pragma unroll
    for (int i = 0; i < 4; ++i) acc[i] = An[i];
    {
      int tn = (t + 1 < T_STEPS) ? t + 1 : 0;
      const float* ap = A + ((size_t)tn * BATCH + rb0 + nl) * HDIM + n0 + q * 4;
      An[0] = *(const f32x4*)(ap);
      An[1] = *(const f32x4*)(ap + 16);
      An[2] = *(const f32x4*)(ap + 32);
      An[3] = *(const f32x4*)(ap + 48);
    }

    // ---- h_{t-1} @ W1h^T, 4 groups x (8 batched ds_reads + 16 MFMAs) -----
    if (t > 0) {
      const bf16* hrow = hr + nl * 512;
#pragma unroll
      for (int g = 0; g < 4; ++g) {
        // batched independent loads (8x ds_read_b128)
        bf16x8 afl = *(bf16x8*)&hrow[((g * 32 + q * 8) ^ sw)];
        bf16x8 af0 = *(bf16x8*)&hrow[(((3 * g + 4) * 32 + q * 8) ^ sw)];
        bf16x8 af1 = *(bf16x8*)&hrow[(((3 * g + 5) * 32 + q * 8) ^ sw)];
        bf16x8 af2 = *(bf16x8*)&hrow[(((3 * g + 6) * 32 + q * 8) ^ sw)];
        bf16x8 wb0 = *(bf16x8*)&Wlds[(size_t)(((w * 4 + 0) * 4 + g) * 64 + lane) * 8];
        bf16x8 wb1 = *(bf16x8*)&Wlds[(size_t)(((w * 4 + 1) * 4 + g) * 64 + lane) * 8];
        bf16x8 wb2 = *(bf16x8*)&Wlds[(size_t)(((w * 4 + 2) * 4 + g) * 64 + lane) * 8];
        bf16x8 wb3 = *(bf16x8*)&Wlds[(size_t)(((w * 4 + 3) * 4 + g) * 64 + lane) * 8];
        // MFMA burst (16)
        __builtin_amdgcn_s_setprio(1);
        acc[0] = __builtin_amdgcn_mfma_f32_16x16x32_bf16(wb0, afl, acc[0], 0, 0, 0);
        acc[1] = __builtin_amdgcn_mfma_f32_16x16x32_bf16(wb1, afl, acc[1], 0, 0, 0);
        acc[2] = __builtin_amdgcn_mfma_f32_16x16x32_bf16(wb2, afl, acc[2], 0, 0, 0);
        acc[3] = __builtin_amdgcn_mfma_f32_16x16x32_bf16(wb3, afl, acc[3], 0, 0, 0);
#pragma unroll
        for (int i = 0; i < 4; ++i)
          acc[i] = __builtin_amdgcn_mfma_f32_16x16x32_bf16(Wreg[i][3 * g + 0], af0, acc[i], 0, 0, 0);
#pragma unroll
        for (int i = 0; i < 4; ++i)
          acc[i] = __builtin_amdgcn_mfma_f32_16x16x32_bf16(Wreg[i][3 * g + 1], af1, acc[i], 0, 0, 0);
#pragma unroll
        for (int i = 0; i < 4; ++i)
          acc[i] = __builtin_amdgcn_mfma_f32_16x16x32_bf16(Wreg[i][3 * g + 2], af2, acc[i], 0, 0, 0);
        __builtin_amdgcn_s_setprio(0);
      }
    }

    if (!DBUF) barrier_lds();   // single-buffer WAR: reads done before overwrite

    // ---- relu; write h_t to hw (swizzled) + Hbf directly from regs -------
#pragma unroll
    for (int i = 0; i < 4; ++i) {
      bf16x4 hv;
#pragma unroll
      for (int r = 0; r < 4; ++r) {
        float v = acc[i][r] > 0.0f ? acc[i][r] : 0.0f;
        hv[r] = (bf16)v;
      }
      *(bf16x4*)&hw[nl * 512 + ((n0 + i * 16 + q * 4) ^ sw)] = hv;
      *(bf16x4*)(Hbf + ((size_t)(rb0 + nl) * T_STEPS + t) * HDIM
                 + n0 + i * 16 + q * 4) = hv;
    }

    barrier_lds();   // h_t visible; orders reads-of-hr vs next-step writes
  }
}

// ---------------------------------------------------------------------------
__global__ __launch_bounds__(256) void copy_hfinal_kernel(
    const bf16* __restrict__ Hbf, float* __restrict__ out)
{
  int i = blockIdx.x * blockDim.x + threadIdx.x;
  int b = i / HDIM, n = i % HDIM;
  out[i] = (float)Hbf[((size_t)b * T_STEPS + (T_STEPS - 1)) * HDIM + n];
}

extern "C" void kernel_launch(void* const* d_in, const int* in_sizes, int n_in,
                              void* d_out, int out_size, void* d_ws, size_t ws_size,
                              hipStream_t stream) {
  const float* x  = (const float*)d_in[0];
  const float* W1 = (const float*)d_in[1];
  const float* b1 = (const float*)d_in[2];
  const float* W2 = (const float*)d_in[3];
  const float* b2 = (const float*)d_in[4];

  float* out = (float*)d_out;
  float* A   = out;   // fp32 x-projection staged in d_out ([T,B,H] order);
                      // consumed by the scan before GEMM3 overwrites it

  bf16* Hbf  = (bf16*)d_ws;   // 32 MB

  // 1) A = X @ W1[:, :E]^T + b1  (bf16 MFMA, fp32 out, rows remapped to [T,B])
  {
    dim3 grid(BATCH * T_STEPS / 128, HDIM / 128);
    gemm_mfma_kernel<float, true><<<grid, 256, 0, stream>>>(
        x, EDIM, W1, EDIM + HDIM, 0, b1, A, HDIM, EDIM);
  }

  // 2) scan. DBUF = 163840 B dynamic LDS (exactly 160 KiB); deterministic
  // fallback to the single-buffer variant.
  {
    int smem_dbuf = (W_ELEMS + 2 * HB_ELEMS) * 2;   // 163840
    int smem_sbuf = (W_ELEMS + 1 * HB_ELEMS) * 2;   // 147456
    hipError_t e = hipFuncSetAttribute(
        reinterpret_cast<const void*>(scan_kernel<1>),
        hipFuncAttributeMaxDynamicSharedMemorySize, smem_dbuf);
    if (e == hipSuccess) {
      scan_kernel<1><<<4, 512, smem_dbuf, stream>>>(A, W1, Hbf);
    } else {
      hipFuncSetAttribute(
          reinterpret_cast<const void*>(scan_kernel<0>),
          hipFuncAttributeMaxDynamicSharedMemorySize, smem_sbuf);
      scan_kernel<0><<<4, 512, smem_sbuf, stream>>>(A, W1, Hbf);
    }
  }

  // 3) outs = Hbf @ W2^T + b2 (overwrites the A staging area)
  {
    dim3 grid(BATCH * T_STEPS / 128, ODIM / 128);
    gemm_mfma_kernel<bf16, false><<<grid, 256, 0, stream>>>(
        Hbf, HDIM, W2, HDIM, 0, b2, out, ODIM, HDIM);
  }

  // 4) h_final tail
  copy_hfinal_kernel<<<(BATCH * HDIM) / 256, 256, 0, stream>>>(
      Hbf, out + (size_t)BATCH * T_STEPS * ODIM);
}

// Round 8
// 2168.892 us; speedup vs baseline: 1.0282x; 1.0282x over previous
//
#include <hip/hip_runtime.h>
#include <cstddef>
#include <type_traits>

#define T_STEPS 512
#define BATCH   64
#define EDIM    512
#define HDIM    512
#define ODIM    512

#define W_ELEMS  (32 * 4 * 64 * 8)  // W kt 0..3: 65536 elems = 131072 B
#define HB_ELEMS (16 * 512)         // one h buffer: 8192 elems = 16384 B

typedef __bf16 bf16;
typedef __bf16 bf16x4 __attribute__((ext_vector_type(4)));
typedef __bf16 bf16x8 __attribute__((ext_vector_type(8)));
typedef float  f32x4  __attribute__((ext_vector_type(4)));

// LDS-only barrier: does NOT drain vmcnt, so in-flight global loads/stores
// (A prefetch, Hbf stores) ride across it. rule-18 fence: sched_barrier after.
__device__ __forceinline__ void barrier_lds() {
  asm volatile("s_waitcnt lgkmcnt(0)\n\ts_barrier" ::: "memory");
  __builtin_amdgcn_sched_barrier(0);
}

// ---------------------------------------------------------------------------
// MFMA GEMM (r6 proven, coalesced staging): C[r,n] = sum_k X[r,k]*W[n,kw0+k]
// + b[n]. 128x128 tile, BK=32, 4 waves. REMAP (proven): rows b*T+t -> t*B+b.
// ---------------------------------------------------------------------------
template <typename XT, bool REMAP>
__global__ __launch_bounds__(256) void gemm_mfma_kernel(
    const XT* __restrict__ X, int ldx,
    const float* __restrict__ W, int ldw, int kw0,
    const float* __restrict__ bias,
    float* __restrict__ C, int ldc, int K)
{
  __shared__ __align__(16) bf16 Asm[8 * 64 * 8];
  __shared__ __align__(16) bf16 Bsm[8 * 64 * 8];

  const int tid  = threadIdx.x;
  const int row0 = blockIdx.x * 128;
  const int col0 = blockIdx.y * 128;
  const int w    = tid >> 6, lane = tid & 63;
  const int q    = lane >> 4, nl = lane & 15;
  const int wm   = w >> 1, wn = w & 1;

  const int srow = tid >> 2;        // 0..63, + rep*64
  const int sq   = tid & 3;         // k-chunk: c0 = sq*8
  f32x4 acc[4][4] = {};

  for (int k0 = 0; k0 < K; k0 += 32) {
#pragma unroll
    for (int rep = 0; rep < 2; ++rep) {
      int rl = srow + rep * 64;                 // row_local 0..127
      int mt = rl >> 4, snl = rl & 15;
      bf16x8 v;
      const XT* src = X + (size_t)(row0 + rl) * ldx + k0 + sq * 8;
      if constexpr (std::is_same_v<XT, float>) {
        f32x4 a0 = *(const f32x4*)src;
        f32x4 a1 = *(const f32x4*)(src + 4);
#pragma unroll
        for (int u = 0; u < 4; ++u) { v[u] = (bf16)a0[u]; v[u + 4] = (bf16)a1[u]; }
      } else {
        v = *(const bf16x8*)src;
      }
      *(bf16x8*)&Asm[(size_t)((mt * 4 + sq) * 16 + snl) * 8] = v;
    }
#pragma unroll
    for (int rep = 0; rep < 2; ++rep) {
      int rl = srow + rep * 64;
      int nt = rl >> 4, snl = rl & 15;
      const float* src = W + (size_t)(col0 + rl) * ldw + kw0 + k0 + sq * 8;
      f32x4 b0 = *(const f32x4*)src;
      f32x4 b1 = *(const f32x4*)(src + 4);
      bf16x8 v;
#pragma unroll
      for (int u = 0; u < 4; ++u) { v[u] = (bf16)b0[u]; v[u + 4] = (bf16)b1[u]; }
      *(bf16x8*)&Bsm[(size_t)((nt * 4 + sq) * 16 + snl) * 8] = v;
    }
    __syncthreads();

    bf16x8 a[4], b[4];
#pragma unroll
    for (int i = 0; i < 4; ++i)
      a[i] = *(bf16x8*)&Asm[(size_t)((wm * 4 + i) * 64 + lane) * 8];
#pragma unroll
    for (int j = 0; j < 4; ++j)
      b[j] = *(bf16x8*)&Bsm[(size_t)((wn * 4 + j) * 64 + lane) * 8];
#pragma unroll
    for (int i = 0; i < 4; ++i)
#pragma unroll
      for (int j = 0; j < 4; ++j)
        acc[i][j] = __builtin_amdgcn_mfma_f32_16x16x32_bf16(a[i], b[j], acc[i][j], 0, 0, 0);
    __syncthreads();
  }

#pragma unroll
  for (int i = 0; i < 4; ++i)
#pragma unroll
    for (int j = 0; j < 4; ++j) {
      int colg = col0 + wn * 64 + j * 16 + nl;
#pragma unroll
      for (int r = 0; r < 4; ++r) {
        size_t rowg = (size_t)(row0 + wm * 64 + i * 16 + q * 4 + r);
        size_t crow = REMAP ? (((rowg & (T_STEPS - 1)) << 6) | (rowg >> 9)) : rowg;
        C[crow * ldc + colg] = acc[i][j][r] + bias[colg];
      }
    }
}

// ---------------------------------------------------------------------------
// Scan, round-8: r6 verbatim (proven 1174 us) EXCEPT one change — the K-loop
// phase order is staggered by wave group:
//   waves 0-3 (one per SIMD): LDS-kts 0..3, then reg-kts 4..15
//   waves 4-7 (one per SIMD): reg-kts 4..15, then LDS-kts 0..3
// r7 post-mortem model: step = LDS 3270 + MFMA 2483 cyc run SERIALLY because
// all 8 waves are barrier-locked into the same phase at the same time.
// m114: MFMA pipe + LDS pipe overlap fully when waves are in DIFFERENT
// phases. With w%4->SIMD mapping, each SIMD now hosts one early-phase and
// one late-phase wave -> matrix pipe fed while LDS pipe drains, both
// directions. Zero traffic / register / barrier change. K-reorder numerics
// proven tolerance-safe by r1/r5 (absmax unchanged at 0.0078125).
// ---------------------------------------------------------------------------
template <int DBUF>
__global__ __launch_bounds__(512, 2) void scan_kernel(
    const float* __restrict__ A,     // [T, B, H] fp32 (t-major, REMAP GEMM)
    const float* __restrict__ W1,    // [H, E+H] fp32
    bf16* __restrict__ Hbf)          // [B, T, H] bf16
{
  extern __shared__ __align__(16) bf16 smem[];
  bf16* Wlds = smem;                       // [tg(32)][kt(4)][lane(64)][8]
  bf16* hb0  = smem + W_ELEMS;             // [16][512] swizzled
  bf16* hb1  = DBUF ? (hb0 + HB_ELEMS) : hb0;

  const int tid  = threadIdx.x;
  const int c    = blockIdx.x;
  const int w    = tid >> 6, lane = tid & 63;
  const int q    = lane >> 4, nl = lane & 15;
  const int rb0  = c * 16;
  const int n0   = w * 64;
  const int sw   = (nl & 7) << 3;          // elem-granularity row swizzle
  const int late = (w >> 2) & 1;           // phase-stagger group

  // ---- one-time: W kt 0..3, all 32 n-tiles -> LDS ------------------------
  for (int idx = tid; idx < 32 * 4 * 64; idx += 512) {
    int l  = idx & 63;
    int kt = (idx >> 6) & 3;
    int tg = idx >> 8;
    int n  = tg * 16 + (l & 15);
    int k  = kt * 32 + (l >> 4) * 8;
    const float* src = W1 + (size_t)n * (EDIM + HDIM) + EDIM + k;
    bf16x8 v;
#pragma unroll
    for (int u = 0; u < 8; ++u) v[u] = (bf16)src[u];
    *(bf16x8*)&Wlds[(size_t)idx * 8] = v;
  }

  // ---- one-time: W kt 4..15 for this wave's 4 tiles -> 192 VGPRs ---------
  bf16x8 Wreg[4][12];
#pragma unroll
  for (int i = 0; i < 4; ++i) {
    int n = n0 + i * 16 + nl;
    const float* wrow = W1 + (size_t)n * (EDIM + HDIM) + EDIM;
#pragma unroll
    for (int kt2 = 0; kt2 < 12; ++kt2) {
      const float* src = wrow + (kt2 + 4) * 32 + q * 8;
      bf16x8 v;
#pragma unroll
      for (int u = 0; u < 8; ++u) v[u] = (bf16)src[u];
      Wreg[i][kt2] = v;
    }
  }
  __syncthreads();

  // ---- prefetch A_0 (4x f32x4; t-major A; proven mapping) ----------------
  f32x4 An[4];
  {
    const float* ap = A + (size_t)(rb0 + nl) * HDIM + n0 + q * 4;
    An[0] = *(const f32x4*)(ap);
    An[1] = *(const f32x4*)(ap + 16);
    An[2] = *(const f32x4*)(ap + 32);
    An[3] = *(const f32x4*)(ap + 48);
  }

  f32x4 acc[4];

  for (int t = 0; t < T_STEPS; ++t) {
    bf16* hr = (t & 1) ? hb1 : hb0;
    bf16* hw = (t & 1) ? hb0 : hb1;

    // ---- acc init from prefetched A_t; issue A_{t+1} prefetch ------------
#pragma unroll
    for (int i = 0; i < 4; ++i) acc[i] = An[i];
    {
      int tn = (t + 1 < T_STEPS) ? t + 1 : 0;
      const float* ap = A + ((size_t)tn * BATCH + rb0 + nl) * HDIM + n0 + q * 4;
      An[0] = *(const f32x4*)(ap);
      An[1] = *(const f32x4*)(ap + 16);
      An[2] = *(const f32x4*)(ap + 32);
      An[3] = *(const f32x4*)(ap + 48);
    }

    // ---- h_{t-1} @ W1h^T over K=512 (operand-swapped MFMA), staggered ----
    if (t > 0) {
      const bf16* hrow = hr + nl * 512;
      if (!late) {
        // LDS-kts first
#pragma unroll
        for (int kt = 0; kt < 4; ++kt) {
          bf16x8 af = *(bf16x8*)&hrow[((kt * 32 + q * 8) ^ sw)];
#pragma unroll
          for (int i = 0; i < 4; ++i) {
            bf16x8 wb = *(bf16x8*)&Wlds[(size_t)(((w * 4 + i) * 4 + kt) * 64 + lane) * 8];
            acc[i] = __builtin_amdgcn_mfma_f32_16x16x32_bf16(wb, af, acc[i], 0, 0, 0);
          }
        }
#pragma unroll
        for (int kt = 4; kt < 16; ++kt) {
          bf16x8 af = *(bf16x8*)&hrow[((kt * 32 + q * 8) ^ sw)];
#pragma unroll
          for (int i = 0; i < 4; ++i)
            acc[i] = __builtin_amdgcn_mfma_f32_16x16x32_bf16(Wreg[i][kt - 4], af, acc[i], 0, 0, 0);
        }
      } else {
        // reg-kts first
#pragma unroll
        for (int kt = 4; kt < 16; ++kt) {
          bf16x8 af = *(bf16x8*)&hrow[((kt * 32 + q * 8) ^ sw)];
#pragma unroll
          for (int i = 0; i < 4; ++i)
            acc[i] = __builtin_amdgcn_mfma_f32_16x16x32_bf16(Wreg[i][kt - 4], af, acc[i], 0, 0, 0);
        }
#pragma unroll
        for (int kt = 0; kt < 4; ++kt) {
          bf16x8 af = *(bf16x8*)&hrow[((kt * 32 + q * 8) ^ sw)];
#pragma unroll
          for (int i = 0; i < 4; ++i) {
            bf16x8 wb = *(bf16x8*)&Wlds[(size_t)(((w * 4 + i) * 4 + kt) * 64 + lane) * 8];
            acc[i] = __builtin_amdgcn_mfma_f32_16x16x32_bf16(wb, af, acc[i], 0, 0, 0);
          }
        }
      }
    }

    if (!DBUF) barrier_lds();   // single-buffer WAR: reads done before overwrite

    // ---- relu; write h_t to hw (swizzled) + Hbf directly from regs -------
#pragma unroll
    for (int i = 0; i < 4; ++i) {
      bf16x4 hv;
#pragma unroll
      for (int r = 0; r < 4; ++r) {
        float v = acc[i][r] > 0.0f ? acc[i][r] : 0.0f;
        hv[r] = (bf16)v;
      }
      *(bf16x4*)&hw[nl * 512 + ((n0 + i * 16 + q * 4) ^ sw)] = hv;
      *(bf16x4*)(Hbf + ((size_t)(rb0 + nl) * T_STEPS + t) * HDIM
                 + n0 + i * 16 + q * 4) = hv;
    }

    barrier_lds();   // h_t visible; orders reads-of-hr vs next-step writes
  }
}

// ---------------------------------------------------------------------------
__global__ __launch_bounds__(256) void copy_hfinal_kernel(
    const bf16* __restrict__ Hbf, float* __restrict__ out)
{
  int i = blockIdx.x * blockDim.x + threadIdx.x;
  int b = i / HDIM, n = i % HDIM;
  out[i] = (float)Hbf[((size_t)b * T_STEPS + (T_STEPS - 1)) * HDIM + n];
}

extern "C" void kernel_launch(void* const* d_in, const int* in_sizes, int n_in,
                              void* d_out, int out_size, void* d_ws, size_t ws_size,
                              hipStream_t stream) {
  const float* x  = (const float*)d_in[0];
  const float* W1 = (const float*)d_in[1];
  const float* b1 = (const float*)d_in[2];
  const float* W2 = (const float*)d_in[3];
  const float* b2 = (const float*)d_in[4];

  float* out = (float*)d_out;
  float* A   = out;   // fp32 x-projection staged in d_out ([T,B,H] order);
                      // consumed by the scan before GEMM3 overwrites it

  bf16* Hbf  = (bf16*)d_ws;   // 32 MB

  // 1) A = X @ W1[:, :E]^T + b1  (bf16 MFMA, fp32 out, rows remapped to [T,B])
  {
    dim3 grid(BATCH * T_STEPS / 128, HDIM / 128);
    gemm_mfma_kernel<float, true><<<grid, 256, 0, stream>>>(
        x, EDIM, W1, EDIM + HDIM, 0, b1, A, HDIM, EDIM);
  }

  // 2) scan. DBUF = 163840 B dynamic LDS (exactly 160 KiB); deterministic
  // fallback to the single-buffer variant.
  {
    int smem_dbuf = (W_ELEMS + 2 * HB_ELEMS) * 2;   // 163840
    int smem_sbuf = (W_ELEMS + 1 * HB_ELEMS) * 2;   // 147456
    hipError_t e = hipFuncSetAttribute(
        reinterpret_cast<const void*>(scan_kernel<1>),
        hipFuncAttributeMaxDynamicSharedMemorySize, smem_dbuf);
    if (e == hipSuccess) {
      scan_kernel<1><<<4, 512, smem_dbuf, stream>>>(A, W1, Hbf);
    } else {
      hipFuncSetAttribute(
          reinterpret_cast<const void*>(scan_kernel<0>),
          hipFuncAttributeMaxDynamicSharedMemorySize, smem_sbuf);
      scan_kernel<0><<<4, 512, smem_sbuf, stream>>>(A, W1, Hbf);
    }
  }

  // 3) outs = Hbf @ W2^T + b2 (overwrites the A staging area)
  {
    dim3 grid(BATCH * T_STEPS / 128, ODIM / 128);
    gemm_mfma_kernel<bf16, false><<<grid, 256, 0, stream>>>(
        Hbf, HDIM, W2, HDIM, 0, b2, out, ODIM, HDIM);
  }

  // 4) h_final tail
  copy_hfinal_kernel<<<(BATCH * HDIM) / 256, 256, 0, stream>>>(
      Hbf, out + (size_t)BATCH * T_STEPS * ODIM);
}

// Round 10
// 1383.711 us; speedup vs baseline: 1.6117x; 1.5674x over previous
//
#include <hip/hip_runtime.h>
#include <cstddef>
#include <type_traits>

#define T_STEPS 512
#define BATCH   64
#define EDIM    512
#define HDIM    512
#define ODIM    512

#define W_ELEMS  (32 * 4 * 64 * 8)  // W kt 0..3: 65536 elems = 131072 B
#define HB_ELEMS (16 * 512)         // one h buffer: 8192 elems = 16384 B

typedef __bf16 bf16;
typedef __bf16 bf16x4 __attribute__((ext_vector_type(4)));
typedef __bf16 bf16x8 __attribute__((ext_vector_type(8)));
typedef float  f32x4  __attribute__((ext_vector_type(4)));

// LDS-only barrier (r6 proven): no vmcnt drain; rule-18 sched fence after.
__device__ __forceinline__ void barrier_lds() {
  asm volatile("s_waitcnt lgkmcnt(0)\n\ts_barrier" ::: "memory");
  __builtin_amdgcn_sched_barrier(0);
}

// global -> LDS direct copy, 16 B/lane. LDS dest must be wave-uniform base;
// HW deposits at base + lane*16 (guide §5).
__device__ __forceinline__ void gload_lds16(const bf16* g, bf16* l) {
  __builtin_amdgcn_global_load_lds(
      (const __attribute__((address_space(1))) unsigned int*)g,
      (__attribute__((address_space(3))) unsigned int*)l, 16, 0, 0);
}

// ---------------------------------------------------------------------------
// fp32 -> bf16 pre-conversion (8 elems/thread, fully coalesced).
// src rows of srow_stride floats; dst compact rows of drow_elems bf16.
// ---------------------------------------------------------------------------
__global__ __launch_bounds__(256) void conv_f32_bf16_kernel(
    const float* __restrict__ src, bf16* __restrict__ dst,
    int srow_stride, int drow_elems)
{
  size_t i = ((size_t)blockIdx.x * 256 + threadIdx.x) * 8;
  size_t row = i / drow_elems, col = i % drow_elems;
  const float* s = src + row * srow_stride + col;
  f32x4 a = *(const f32x4*)s;
  f32x4 b = *(const f32x4*)(s + 4);
  bf16x8 v;
#pragma unroll
  for (int u = 0; u < 4; ++u) { v[u] = (bf16)a[u]; v[u + 4] = (bf16)b[u]; }
  *(bf16x8*)(dst + i) = v;
}

// ---------------------------------------------------------------------------
// MFMA GEMM fallback (r6 proven, coalesced reg-staging). Used only when
// ws_size can't host the bf16-converted operands.
// ---------------------------------------------------------------------------
template <typename XT, bool REMAP>
__global__ __launch_bounds__(256) void gemm_mfma_kernel(
    const XT* __restrict__ X, int ldx,
    const float* __restrict__ W, int ldw, int kw0,
    const float* __restrict__ bias,
    float* __restrict__ C, int ldc, int K)
{
  __shared__ __align__(16) bf16 Asm[8 * 64 * 8];
  __shared__ __align__(16) bf16 Bsm[8 * 64 * 8];

  const int tid  = threadIdx.x;
  const int row0 = blockIdx.x * 128;
  const int col0 = blockIdx.y * 128;
  const int w    = tid >> 6, lane = tid & 63;
  const int q    = lane >> 4, nl = lane & 15;
  const int wm   = w >> 1, wn = w & 1;

  const int srow = tid >> 2;
  const int sq   = tid & 3;
  f32x4 acc[4][4] = {};

  for (int k0 = 0; k0 < K; k0 += 32) {
#pragma unroll
    for (int rep = 0; rep < 2; ++rep) {
      int rl = srow + rep * 64;
      int mt = rl >> 4, snl = rl & 15;
      bf16x8 v;
      const XT* src = X + (size_t)(row0 + rl) * ldx + k0 + sq * 8;
      if constexpr (std::is_same_v<XT, float>) {
        f32x4 a0 = *(const f32x4*)src;
        f32x4 a1 = *(const f32x4*)(src + 4);
#pragma unroll
        for (int u = 0; u < 4; ++u) { v[u] = (bf16)a0[u]; v[u + 4] = (bf16)a1[u]; }
      } else {
        v = *(const bf16x8*)src;
      }
      *(bf16x8*)&Asm[(size_t)((mt * 4 + sq) * 16 + snl) * 8] = v;
    }
#pragma unroll
    for (int rep = 0; rep < 2; ++rep) {
      int rl = srow + rep * 64;
      int nt = rl >> 4, snl = rl & 15;
      const float* src = W + (size_t)(col0 + rl) * ldw + kw0 + k0 + sq * 8;
      f32x4 b0 = *(const f32x4*)src;
      f32x4 b1 = *(const f32x4*)(src + 4);
      bf16x8 v;
#pragma unroll
      for (int u = 0; u < 4; ++u) { v[u] = (bf16)b0[u]; v[u + 4] = (bf16)b1[u]; }
      *(bf16x8*)&Bsm[(size_t)((nt * 4 + sq) * 16 + snl) * 8] = v;
    }
    __syncthreads();

    bf16x8 a[4], b[4];
#pragma unroll
    for (int i = 0; i < 4; ++i)
      a[i] = *(bf16x8*)&Asm[(size_t)((wm * 4 + i) * 64 + lane) * 8];
#pragma unroll
    for (int j = 0; j < 4; ++j)
      b[j] = *(bf16x8*)&Bsm[(size_t)((wn * 4 + j) * 64 + lane) * 8];
#pragma unroll
    for (int i = 0; i < 4; ++i)
#pragma unroll
      for (int j = 0; j < 4; ++j)
        acc[i][j] = __builtin_amdgcn_mfma_f32_16x16x32_bf16(a[i], b[j], acc[i][j], 0, 0, 0);
    __syncthreads();
  }

#pragma unroll
  for (int i = 0; i < 4; ++i)
#pragma unroll
    for (int j = 0; j < 4; ++j) {
      int colg = col0 + wn * 64 + j * 16 + nl;
#pragma unroll
      for (int r = 0; r < 4; ++r) {
        size_t rowg = (size_t)(row0 + wm * 64 + i * 16 + q * 4 + r);
        size_t crow = REMAP ? (((rowg & (T_STEPS - 1)) << 6) | (rowg >> 9)) : rowg;
        C[crow * ldc + colg] = acc[i][j][r] + bias[colg];
      }
    }
}

// ---------------------------------------------------------------------------
// MFMA GEMM fast path: both operands bf16 in global, staged via
// global_load_lds width=16 (m97 recipe: no VGPR round-trip, no cvt VALU).
// Source mapping chosen so the wave-linear LDS write reproduces the EXACT
// proven fragment layout: idx = tid + rep*256; dest elems [idx*8, +8);
// layout elem = (mt*64 + sq*16 + snl)*8  ->  mt=idx>>6, sq=(idx>>4)&3,
// snl=idx&15; source = row (row0+mt*16+snl), k-chunk sq. All addresses
// 16B-aligned (row strides multiples of 8 elems; k0+sq*8 elems = 16B mult).
// MFMA phase + epilogue byte-identical to the proven kernel.
// ---------------------------------------------------------------------------
template <bool REMAP>
__global__ __launch_bounds__(256) void gemm_lds_kernel(
    const bf16* __restrict__ Abf, int lda,
    const bf16* __restrict__ Bbf, int ldb,
    const float* __restrict__ bias,
    float* __restrict__ C, int ldc, int K)
{
  __shared__ __align__(16) bf16 Asm[8 * 64 * 8];
  __shared__ __align__(16) bf16 Bsm[8 * 64 * 8];

  const int tid  = threadIdx.x;
  const int row0 = blockIdx.x * 128;
  const int col0 = blockIdx.y * 128;
  const int w    = tid >> 6, lane = tid & 63;
  const int q    = lane >> 4, nl = lane & 15;
  const int wm   = w >> 1, wn = w & 1;

  f32x4 acc[4][4] = {};

  for (int k0 = 0; k0 < K; k0 += 32) {
#pragma unroll
    for (int rep = 0; rep < 2; ++rep) {
      int idx = tid + rep * 256;
      int mt = idx >> 6, sq = (idx >> 4) & 3, snl = idx & 15;
      const bf16* ga = Abf + (size_t)(row0 + mt * 16 + snl) * lda + k0 + sq * 8;
      gload_lds16(ga, Asm + (size_t)(rep * 4 + w) * 512);
      const bf16* gb = Bbf + (size_t)(col0 + mt * 16 + snl) * ldb + k0 + sq * 8;
      gload_lds16(gb, Bsm + (size_t)(rep * 4 + w) * 512);
    }
    __syncthreads();   // drains vmcnt: staged tiles complete

    bf16x8 a[4], b[4];
#pragma unroll
    for (int i = 0; i < 4; ++i)
      a[i] = *(bf16x8*)&Asm[(size_t)((wm * 4 + i) * 64 + lane) * 8];
#pragma unroll
    for (int j = 0; j < 4; ++j)
      b[j] = *(bf16x8*)&Bsm[(size_t)((wn * 4 + j) * 64 + lane) * 8];
#pragma unroll
    for (int i = 0; i < 4; ++i)
#pragma unroll
      for (int j = 0; j < 4; ++j)
        acc[i][j] = __builtin_amdgcn_mfma_f32_16x16x32_bf16(a[i], b[j], acc[i][j], 0, 0, 0);
    __syncthreads();
  }

#pragma unroll
  for (int i = 0; i < 4; ++i)
#pragma unroll
    for (int j = 0; j < 4; ++j) {
      int colg = col0 + wn * 64 + j * 16 + nl;
#pragma unroll
      for (int r = 0; r < 4; ++r) {
        size_t rowg = (size_t)(row0 + wm * 64 + i * 16 + q * 4 + r);
        size_t crow = REMAP ? (((rowg & (T_STEPS - 1)) << 6) | (rowg >> 9)) : rowg;
        C[crow * ldc + colg] = acc[i][j][r] + bias[colg];
      }
    }
}

// ---------------------------------------------------------------------------
// Scan (r6 VERBATIM, proven 1174 us; r7/r8 proved any K-loop reshaping
// regresses ~70% — the compiler's schedule of this form is the optimum).
// ---------------------------------------------------------------------------
template <int DBUF>
__global__ __launch_bounds__(512, 2) void scan_kernel(
    const float* __restrict__ A,     // [T, B, H] fp32 (t-major, REMAP GEMM)
    const float* __restrict__ W1,    // [H, E+H] fp32
    bf16* __restrict__ Hbf)          // [B, T, H] bf16
{
  extern __shared__ __align__(16) bf16 smem[];
  bf16* Wlds = smem;                       // [tg(32)][kt(4)][lane(64)][8]
  bf16* hb0  = smem + W_ELEMS;             // [16][512] swizzled
  bf16* hb1  = DBUF ? (hb0 + HB_ELEMS) : hb0;

  const int tid  = threadIdx.x;
  const int c    = blockIdx.x;
  const int w    = tid >> 6, lane = tid & 63;
  const int q    = lane >> 4, nl = lane & 15;
  const int rb0  = c * 16;
  const int n0   = w * 64;
  const int sw   = (nl & 7) << 3;          // elem-granularity row swizzle

  // ---- one-time: W kt 0..3, all 32 n-tiles -> LDS ------------------------
  for (int idx = tid; idx < 32 * 4 * 64; idx += 512) {
    int l  = idx & 63;
    int kt = (idx >> 6) & 3;
    int tg = idx >> 8;
    int n  = tg * 16 + (l & 15);
    int k  = kt * 32 + (l >> 4) * 8;
    const float* src = W1 + (size_t)n * (EDIM + HDIM) + EDIM + k;
    bf16x8 v;
#pragma unroll
    for (int u = 0; u < 8; ++u) v[u] = (bf16)src[u];
    *(bf16x8*)&Wlds[(size_t)idx * 8] = v;
  }

  // ---- one-time: W kt 4..15 for this wave's 4 tiles -> 192 VGPRs ---------
  bf16x8 Wreg[4][12];
#pragma unroll
  for (int i = 0; i < 4; ++i) {
    int n = n0 + i * 16 + nl;
    const float* wrow = W1 + (size_t)n * (EDIM + HDIM) + EDIM;
#pragma unroll
    for (int kt2 = 0; kt2 < 12; ++kt2) {
      const float* src = wrow + (kt2 + 4) * 32 + q * 8;
      bf16x8 v;
#pragma unroll
      for (int u = 0; u < 8; ++u) v[u] = (bf16)src[u];
      Wreg[i][kt2] = v;
    }
  }
  __syncthreads();

  // ---- prefetch A_0 (4x f32x4; t-major A; proven mapping) ----------------
  f32x4 An[4];
  {
    const float* ap = A + (size_t)(rb0 + nl) * HDIM + n0 + q * 4;
    An[0] = *(const f32x4*)(ap);
    An[1] = *(const f32x4*)(ap + 16);
    An[2] = *(const f32x4*)(ap + 32);
    An[3] = *(const f32x4*)(ap + 48);
  }

  f32x4 acc[4];

  for (int t = 0; t < T_STEPS; ++t) {
    bf16* hr = (t & 1) ? hb1 : hb0;
    bf16* hw = (t & 1) ? hb0 : hb1;

    // ---- acc init from prefetched A_t; issue A_{t+1} prefetch ------------
#pragma unroll
    for (int i = 0; i < 4; ++i) acc[i] = An[i];
    {
      int tn = (t + 1 < T_STEPS) ? t + 1 : 0;
      const float* ap = A + ((size_t)tn * BATCH + rb0 + nl) * HDIM + n0 + q * 4;
      An[0] = *(const f32x4*)(ap);
      An[1] = *(const f32x4*)(ap + 16);
      An[2] = *(const f32x4*)(ap + 32);
      An[3] = *(const f32x4*)(ap + 48);
    }

    // ---- h_{t-1} @ W1h^T over K=512 (operand-swapped MFMA) ---------------
    if (t > 0) {
#pragma unroll
      for (int kt = 0; kt < 16; ++kt) {
        bf16x8 af = *(bf16x8*)&hr[nl * 512 + ((kt * 32 + q * 8) ^ sw)];
        if (kt < 4) {
#pragma unroll
          for (int i = 0; i < 4; ++i) {
            bf16x8 wb = *(bf16x8*)&Wlds[(size_t)(((w * 4 + i) * 4 + kt) * 64 + lane) * 8];
            acc[i] = __builtin_amdgcn_mfma_f32_16x16x32_bf16(wb, af, acc[i], 0, 0, 0);
          }
        } else {
#pragma unroll
          for (int i = 0; i < 4; ++i)
            acc[i] = __builtin_amdgcn_mfma_f32_16x16x32_bf16(Wreg[i][kt - 4], af, acc[i], 0, 0, 0);
        }
      }
    }

    if (!DBUF) barrier_lds();   // single-buffer WAR: reads done before overwrite

    // ---- relu; write h_t to hw (swizzled) + Hbf directly from regs -------
#pragma unroll
    for (int i = 0; i < 4; ++i) {
      bf16x4 hv;
#pragma unroll
      for (int r = 0; r < 4; ++r) {
        float v = acc[i][r] > 0.0f ? acc[i][r] : 0.0f;
        hv[r] = (bf16)v;
      }
      *(bf16x4*)&hw[nl * 512 + ((n0 + i * 16 + q * 4) ^ sw)] = hv;
      *(bf16x4*)(Hbf + ((size_t)(rb0 + nl) * T_STEPS + t) * HDIM
                 + n0 + i * 16 + q * 4) = hv;
    }

    barrier_lds();   // h_t visible; orders reads-of-hr vs next-step writes
  }
}

// ---------------------------------------------------------------------------
__global__ __launch_bounds__(256) void copy_hfinal_kernel(
    const bf16* __restrict__ Hbf, float* __restrict__ out)
{
  int i = blockIdx.x * blockDim.x + threadIdx.x;
  int b = i / HDIM, n = i % HDIM;
  out[i] = (float)Hbf[((size_t)b * T_STEPS + (T_STEPS - 1)) * HDIM + n];
}

extern "C" void kernel_launch(void* const* d_in, const int* in_sizes, int n_in,
                              void* d_out, int out_size, void* d_ws, size_t ws_size,
                              hipStream_t stream) {
  const float* x  = (const float*)d_in[0];
  const float* W1 = (const float*)d_in[1];
  const float* b1 = (const float*)d_in[2];
  const float* W2 = (const float*)d_in[3];
  const float* b2 = (const float*)d_in[4];

  float* out = (float*)d_out;
  float* A   = out;   // fp32 x-projection staged in d_out ([T,B,H] order)

  // workspace layout (runtime-gated):
  //   [0, 32M)        Hbf
  //   [32M, +512K)    W1b  (bf16 of W1[:, :E], compact [H][E])
  //   [+512K, +512K)  W2b  (bf16 of W2, [O][H])
  //   [33M, +32M)     xbf  (bf16 of x, [B*T][E])
  bf16*  Hbf   = (bf16*)d_ws;
  size_t HBF_B = (size_t)BATCH * T_STEPS * HDIM * 2;          // 33,554,432
  bf16*  W1b   = (bf16*)((char*)d_ws + HBF_B);
  bf16*  W2b   = (bf16*)((char*)d_ws + HBF_B + 524288);
  bf16*  xbf   = (bf16*)((char*)d_ws + HBF_B + 1048576);
  const bool wok = ws_size >= HBF_B + 1048576;                 // W2b fits
  const bool xok = ws_size >= HBF_B + 1048576 + HBF_B;         // xbf fits too

  // 0) pre-conversions (bf16 rounding identical to in-staging conversion)
  if (xok) {
    conv_f32_bf16_kernel<<<(BATCH * T_STEPS * EDIM) / 2048, 256, 0, stream>>>(
        x, xbf, EDIM, EDIM);
    conv_f32_bf16_kernel<<<(HDIM * EDIM) / 2048, 256, 0, stream>>>(
        W1, W1b, EDIM + HDIM, EDIM);
  }
  if (wok) {
    conv_f32_bf16_kernel<<<(ODIM * HDIM) / 2048, 256, 0, stream>>>(
        W2, W2b, HDIM, HDIM);
  }

  // 1) A = X @ W1[:, :E]^T + b1  (fp32 out, rows remapped to [T,B])
  {
    dim3 grid(BATCH * T_STEPS / 128, HDIM / 128);
    if (xok)
      gemm_lds_kernel<true><<<grid, 256, 0, stream>>>(
          xbf, EDIM, W1b, EDIM, b1, A, HDIM, EDIM);
    else
      gemm_mfma_kernel<float, true><<<grid, 256, 0, stream>>>(
          x, EDIM, W1, EDIM + HDIM, 0, b1, A, HDIM, EDIM);
  }

  // 2) scan (r6 proven, untouched)
  {
    int smem_dbuf = (W_ELEMS + 2 * HB_ELEMS) * 2;   // 163840
    int smem_sbuf = (W_ELEMS + 1 * HB_ELEMS) * 2;   // 147456
    hipError_t e = hipFuncSetAttribute(
        reinterpret_cast<const void*>(scan_kernel<1>),
        hipFuncAttributeMaxDynamicSharedMemorySize, smem_dbuf);
    if (e == hipSuccess) {
      scan_kernel<1><<<4, 512, smem_dbuf, stream>>>(A, W1, Hbf);
    } else {
      hipFuncSetAttribute(
          reinterpret_cast<const void*>(scan_kernel<0>),
          hipFuncAttributeMaxDynamicSharedMemorySize, smem_sbuf);
      scan_kernel<0><<<4, 512, smem_sbuf, stream>>>(A, W1, Hbf);
    }
  }

  // 3) outs = Hbf @ W2^T + b2 (overwrites the A staging area)
  {
    dim3 grid(BATCH * T_STEPS / 128, ODIM / 128);
    if (wok)
      gemm_lds_kernel<false><<<grid, 256, 0, stream>>>(
          Hbf, HDIM, W2b, HDIM, b2, out, ODIM, HDIM);
    else
      gemm_mfma_kernel<bf16, false><<<grid, 256, 0, stream>>>(
          Hbf, HDIM, W2, HDIM, 0, b2, out, ODIM, HDIM);
  }

  // 4) h_final tail
  copy_hfinal_kernel<<<(BATCH * HDIM) / 256, 256, 0, stream>>>(
      Hbf, out + (size_t)BATCH * T_STEPS * ODIM);
}

// Round 11
// 1382.766 us; speedup vs baseline: 1.6128x; 1.0007x over previous
//
#include <hip/hip_runtime.h>
#include <cstddef>
#include <type_traits>

#define T_STEPS 512
#define BATCH   64
#define EDIM    512
#define HDIM    512
#define ODIM    512

#define W_ELEMS  (32 * 4 * 64 * 8)  // W kt 0..3: 65536 elems = 131072 B
#define HB_ELEMS (16 * 512)         // one h buffer: 8192 elems = 16384 B
#define SMEM_COOP ((W_ELEMS + 2 * HB_ELEMS) * 2)   // 163840 = 160 KiB

typedef __bf16 bf16;
typedef __bf16 bf16x4 __attribute__((ext_vector_type(4)));
typedef __bf16 bf16x8 __attribute__((ext_vector_type(8)));
typedef float  f32x4  __attribute__((ext_vector_type(4)));

// LDS-only barrier (r6 proven): no vmcnt drain; rule-18 sched fence after.
__device__ __forceinline__ void barrier_lds() {
  asm volatile("s_waitcnt lgkmcnt(0)\n\ts_barrier" ::: "memory");
  __builtin_amdgcn_sched_barrier(0);
}

// global -> LDS direct copy, 16 B/lane (wave-uniform LDS base).
__device__ __forceinline__ void gload_lds16(const bf16* g, bf16* l) {
  __builtin_amdgcn_global_load_lds(
      (const __attribute__((address_space(1))) unsigned int*)g,
      (__attribute__((address_space(3))) unsigned int*)l, 16, 0, 0);
}

// ---------------------------------------------------------------------------
// fp32 -> bf16 conversion (coop path: W2 only). Coalesced, 8 elems/thread.
// ---------------------------------------------------------------------------
__global__ __launch_bounds__(256) void conv_f32_bf16_kernel(
    const float* __restrict__ src, bf16* __restrict__ dst,
    int srow_stride, int drow_elems)
{
  size_t i = ((size_t)blockIdx.x * 256 + threadIdx.x) * 8;
  size_t row = i / drow_elems, col = i % drow_elems;
  const float* s = src + row * srow_stride + col;
  f32x4 a = *(const f32x4*)s;
  f32x4 b = *(const f32x4*)(s + 4);
  bf16x8 v;
#pragma unroll
  for (int u = 0; u < 4; ++u) { v[u] = (bf16)a[u]; v[u + 4] = (bf16)b[u]; }
  *(bf16x8*)(dst + i) = v;
}

// ---------------------------------------------------------------------------
// MFMA GEMM (r6 proven, coalesced reg-staging): C[r,n]=sum_k X[r,k]*W[n,kw0+k]
// + b[n]. 128x128 tile, BK=32, 4 waves. REMAP: rows b*T+t -> t*B+b.
// ---------------------------------------------------------------------------
template <typename XT, bool REMAP>
__global__ __launch_bounds__(256) void gemm_mfma_kernel(
    const XT* __restrict__ X, int ldx,
    const float* __restrict__ W, int ldw, int kw0,
    const float* __restrict__ bias,
    float* __restrict__ C, int ldc, int K)
{
  __shared__ __align__(16) bf16 Asm[8 * 64 * 8];
  __shared__ __align__(16) bf16 Bsm[8 * 64 * 8];

  const int tid  = threadIdx.x;
  const int row0 = blockIdx.x * 128;
  const int col0 = blockIdx.y * 128;
  const int w    = tid >> 6, lane = tid & 63;
  const int q    = lane >> 4, nl = lane & 15;
  const int wm   = w >> 1, wn = w & 1;

  const int srow = tid >> 2;
  const int sq   = tid & 3;
  f32x4 acc[4][4] = {};

  for (int k0 = 0; k0 < K; k0 += 32) {
#pragma unroll
    for (int rep = 0; rep < 2; ++rep) {
      int rl = srow + rep * 64;
      int mt = rl >> 4, snl = rl & 15;
      bf16x8 v;
      const XT* src = X + (size_t)(row0 + rl) * ldx + k0 + sq * 8;
      if constexpr (std::is_same_v<XT, float>) {
        f32x4 a0 = *(const f32x4*)src;
        f32x4 a1 = *(const f32x4*)(src + 4);
#pragma unroll
        for (int u = 0; u < 4; ++u) { v[u] = (bf16)a0[u]; v[u + 4] = (bf16)a1[u]; }
      } else {
        v = *(const bf16x8*)src;
      }
      *(bf16x8*)&Asm[(size_t)((mt * 4 + sq) * 16 + snl) * 8] = v;
    }
#pragma unroll
    for (int rep = 0; rep < 2; ++rep) {
      int rl = srow + rep * 64;
      int nt = rl >> 4, snl = rl & 15;
      const float* src = W + (size_t)(col0 + rl) * ldw + kw0 + k0 + sq * 8;
      f32x4 b0 = *(const f32x4*)src;
      f32x4 b1 = *(const f32x4*)(src + 4);
      bf16x8 v;
#pragma unroll
      for (int u = 0; u < 4; ++u) { v[u] = (bf16)b0[u]; v[u + 4] = (bf16)b1[u]; }
      *(bf16x8*)&Bsm[(size_t)((nt * 4 + sq) * 16 + snl) * 8] = v;
    }
    __syncthreads();

    bf16x8 a[4], b[4];
#pragma unroll
    for (int i = 0; i < 4; ++i)
      a[i] = *(bf16x8*)&Asm[(size_t)((wm * 4 + i) * 64 + lane) * 8];
#pragma unroll
    for (int j = 0; j < 4; ++j)
      b[j] = *(bf16x8*)&Bsm[(size_t)((wn * 4 + j) * 64 + lane) * 8];
#pragma unroll
    for (int i = 0; i < 4; ++i)
#pragma unroll
      for (int j = 0; j < 4; ++j)
        acc[i][j] = __builtin_amdgcn_mfma_f32_16x16x32_bf16(a[i], b[j], acc[i][j], 0, 0, 0);
    __syncthreads();
  }

#pragma unroll
  for (int i = 0; i < 4; ++i)
#pragma unroll
    for (int j = 0; j < 4; ++j) {
      int colg = col0 + wn * 64 + j * 16 + nl;
#pragma unroll
      for (int r = 0; r < 4; ++r) {
        size_t rowg = (size_t)(row0 + wm * 64 + i * 16 + q * 4 + r);
        size_t crow = REMAP ? (((rowg & (T_STEPS - 1)) << 6) | (rowg >> 9)) : rowg;
        C[crow * ldc + colg] = acc[i][j][r] + bias[colg];
      }
    }
}

// ---------------------------------------------------------------------------
// Scan body (r6 VERBATIM logic; r7/r8 proved any K-loop reshaping regresses).
// PUB adds a coarse progress publish every 64 steps (coop path only):
// all-threads vmcnt drain -> barrier -> tid0 {threadfence (L2 writeback to
// the agent coherence point) + agent-scope flag}. 8 publishes total.
// ---------------------------------------------------------------------------
template <int DBUF, bool PUB>
__device__ __forceinline__ void scan_body(
    const float* __restrict__ A,     // [T, B, H] fp32 (t-major, REMAP GEMM)
    const float* __restrict__ W1,    // [H, E+H] fp32
    bf16* __restrict__ Hbf,          // [B, T, H] bf16
    bf16* smem, int c, int* prog)
{
  bf16* Wlds = smem;                       // [tg(32)][kt(4)][lane(64)][8]
  bf16* hb0  = smem + W_ELEMS;             // [16][512] swizzled
  bf16* hb1  = DBUF ? (hb0 + HB_ELEMS) : hb0;

  const int tid  = threadIdx.x;
  const int w    = tid >> 6, lane = tid & 63;
  const int q    = lane >> 4, nl = lane & 15;
  const int rb0  = c * 16;
  const int n0   = w * 64;
  const int sw   = (nl & 7) << 3;          // elem-granularity row swizzle

  // ---- one-time: W kt 0..3, all 32 n-tiles -> LDS ------------------------
  for (int idx = tid; idx < 32 * 4 * 64; idx += 512) {
    int l  = idx & 63;
    int kt = (idx >> 6) & 3;
    int tg = idx >> 8;
    int n  = tg * 16 + (l & 15);
    int k  = kt * 32 + (l >> 4) * 8;
    const float* src = W1 + (size_t)n * (EDIM + HDIM) + EDIM + k;
    bf16x8 v;
#pragma unroll
    for (int u = 0; u < 8; ++u) v[u] = (bf16)src[u];
    *(bf16x8*)&Wlds[(size_t)idx * 8] = v;
  }

  // ---- one-time: W kt 4..15 for this wave's 4 tiles -> 192 VGPRs ---------
  bf16x8 Wreg[4][12];
#pragma unroll
  for (int i = 0; i < 4; ++i) {
    int n = n0 + i * 16 + nl;
    const float* wrow = W1 + (size_t)n * (EDIM + HDIM) + EDIM;
#pragma unroll
    for (int kt2 = 0; kt2 < 12; ++kt2) {
      const float* src = wrow + (kt2 + 4) * 32 + q * 8;
      bf16x8 v;
#pragma unroll
      for (int u = 0; u < 8; ++u) v[u] = (bf16)src[u];
      Wreg[i][kt2] = v;
    }
  }
  __syncthreads();

  // ---- prefetch A_0 ------------------------------------------------------
  f32x4 An[4];
  {
    const float* ap = A + (size_t)(rb0 + nl) * HDIM + n0 + q * 4;
    An[0] = *(const f32x4*)(ap);
    An[1] = *(const f32x4*)(ap + 16);
    An[2] = *(const f32x4*)(ap + 32);
    An[3] = *(const f32x4*)(ap + 48);
  }

  f32x4 acc[4];

  for (int t = 0; t < T_STEPS; ++t) {
    bf16* hr = (t & 1) ? hb1 : hb0;
    bf16* hw = (t & 1) ? hb0 : hb1;

#pragma unroll
    for (int i = 0; i < 4; ++i) acc[i] = An[i];
    {
      int tn = (t + 1 < T_STEPS) ? t + 1 : 0;
      const float* ap = A + ((size_t)tn * BATCH + rb0 + nl) * HDIM + n0 + q * 4;
      An[0] = *(const f32x4*)(ap);
      An[1] = *(const f32x4*)(ap + 16);
      An[2] = *(const f32x4*)(ap + 32);
      An[3] = *(const f32x4*)(ap + 48);
    }

    if (t > 0) {
#pragma unroll
      for (int kt = 0; kt < 16; ++kt) {
        bf16x8 af = *(bf16x8*)&hr[nl * 512 + ((kt * 32 + q * 8) ^ sw)];
        if (kt < 4) {
#pragma unroll
          for (int i = 0; i < 4; ++i) {
            bf16x8 wb = *(bf16x8*)&Wlds[(size_t)(((w * 4 + i) * 4 + kt) * 64 + lane) * 8];
            acc[i] = __builtin_amdgcn_mfma_f32_16x16x32_bf16(wb, af, acc[i], 0, 0, 0);
          }
        } else {
#pragma unroll
          for (int i = 0; i < 4; ++i)
            acc[i] = __builtin_amdgcn_mfma_f32_16x16x32_bf16(Wreg[i][kt - 4], af, acc[i], 0, 0, 0);
        }
      }
    }

    if (!DBUF) barrier_lds();

#pragma unroll
    for (int i = 0; i < 4; ++i) {
      bf16x4 hv;
#pragma unroll
      for (int r = 0; r < 4; ++r) {
        float v = acc[i][r] > 0.0f ? acc[i][r] : 0.0f;
        hv[r] = (bf16)v;
      }
      *(bf16x4*)&hw[nl * 512 + ((n0 + i * 16 + q * 4) ^ sw)] = hv;
      *(bf16x4*)(Hbf + ((size_t)(rb0 + nl) * T_STEPS + t) * HDIM
                 + n0 + i * 16 + q * 4) = hv;
    }

    barrier_lds();   // h_t visible; orders reads-of-hr vs next-step writes

    if constexpr (PUB) {
      if ((t & 63) == 63) {
        asm volatile("s_waitcnt vmcnt(0)" ::: "memory");  // own Hbf stores in L2
        __syncthreads();                                  // ... for ALL threads
        if (tid == 0) {
          __threadfence();                                // L2 -> coherence point
          __hip_atomic_store(prog + c * 32, t + 1, __ATOMIC_RELAXED,
                             __HIP_MEMORY_SCOPE_AGENT);
        }
      }
    }
  }
}

template <int DBUF>
__global__ __launch_bounds__(512, 2) void scan_kernel(
    const float* __restrict__ A, const float* __restrict__ W1,
    bf16* __restrict__ Hbf)
{
  extern __shared__ __align__(16) bf16 smem[];
  scan_body<DBUF, false>(A, W1, Hbf, smem, blockIdx.x, nullptr);
}

// ---------------------------------------------------------------------------
// Cooperative fused kernel: 256 blocks x 512 threads, 160 KiB dynamic LDS
// (=> exactly 1 block/CU; co-residency GUARANTEED by cooperative launch, so
// worker spin-waits cannot starve the scan — the r1/r5 fatality was per-step
// sync; here sync is 8 coarse publishes).
//   blocks 0..3  : scan clusters (r6 body + publish)
//   blocks 4..255: persistent GEMM3 workers. 1024 tiles (128x128), ordered
//     t-chunk-major so early chunks compute while the scan is mid-flight.
//     Per tile: poll progress[b/16] >= t0+128 (agent atomic reads through to
//     the coherence point), acquire-fence (invalidate stale L1/L2 — needed
//     because graph re-execution can leave stale Hbf lines), then a 4-wave
//     128x128 gload_lds GEMM (threads 256..511 idle through barriers).
// C writes go to d_out; A lives in WORKSPACE (not d_out) so overlap cannot
// alias the scan's unread A rows.
// ---------------------------------------------------------------------------
__global__ __launch_bounds__(512, 2) void coop_kernel(
    const float* __restrict__ A, const float* __restrict__ W1,
    bf16* __restrict__ Hbf, const bf16* __restrict__ W2b,
    const float* __restrict__ b2, float* __restrict__ out,
    int* __restrict__ progress)
{
  extern __shared__ __align__(16) bf16 smem[];
  const int bid = blockIdx.x;
  const int tid = threadIdx.x;

  if (bid < 4) {
    scan_body<1, true>(A, W1, Hbf, smem, bid, progress);
    return;
  }

  // ---------------- GEMM3 worker ------------------------------------------
  bf16* Asm = smem;                 // 8 KB
  bf16* Bsm = smem + 8 * 64 * 8;    // 8 KB

  const int wid  = bid - 4;                 // 0..251
  const bool act = tid < 256;
  const int w    = (tid >> 6) & 3, lane = tid & 63;
  const int q    = lane >> 4, nl = lane & 15;
  const int wm   = w >> 1, wn = w & 1;

  for (int g = wid; g < 1024; g += 252) {
    int tc = g >> 8;                        // t-chunk 0..3 (ascending)
    int b  = (g >> 2) & 63;
    int by = g & 3;
    int row0 = b * 512 + tc * 128;          // rows = b*T + t, t in [tc*128,+128)
    int col0 = by * 128;
    int need = tc * 128 + 128;

    if (tid == 0) {
      while (__hip_atomic_load(progress + (b >> 4) * 32, __ATOMIC_RELAXED,
                               __HIP_MEMORY_SCOPE_AGENT) < need)
        __builtin_amdgcn_s_sleep(8);
      __threadfence();                      // acquire: invalidate stale caches
    }
    __syncthreads();

    f32x4 acc[4][4] = {};
    for (int k0 = 0; k0 < HDIM; k0 += 32) {
      if (act) {
#pragma unroll
        for (int rep = 0; rep < 2; ++rep) {
          int idx = tid + rep * 256;
          int mt = idx >> 6, sq = (idx >> 4) & 3, snl = idx & 15;
          gload_lds16(Hbf + (size_t)(row0 + mt * 16 + snl) * HDIM + k0 + sq * 8,
                      Asm + (size_t)(rep * 4 + w) * 512);
          gload_lds16(W2b + (size_t)(col0 + mt * 16 + snl) * HDIM + k0 + sq * 8,
                      Bsm + (size_t)(rep * 4 + w) * 512);
        }
      }
      __syncthreads();                      // drains vmcnt: tiles staged
      if (act) {
        bf16x8 a[4], bb[4];
#pragma unroll
        for (int i = 0; i < 4; ++i)
          a[i] = *(bf16x8*)&Asm[(size_t)((wm * 4 + i) * 64 + lane) * 8];
#pragma unroll
        for (int j = 0; j < 4; ++j)
          bb[j] = *(bf16x8*)&Bsm[(size_t)((wn * 4 + j) * 64 + lane) * 8];
#pragma unroll
        for (int i = 0; i < 4; ++i)
#pragma unroll
          for (int j = 0; j < 4; ++j)
            acc[i][j] = __builtin_amdgcn_mfma_f32_16x16x32_bf16(a[i], bb[j], acc[i][j], 0, 0, 0);
      }
      __syncthreads();
    }

    if (act) {
#pragma unroll
      for (int i = 0; i < 4; ++i)
#pragma unroll
        for (int j = 0; j < 4; ++j) {
          int colg = col0 + wn * 64 + j * 16 + nl;
#pragma unroll
          for (int r = 0; r < 4; ++r) {
            size_t rowg = (size_t)(row0 + wm * 64 + i * 16 + q * 4 + r);
            out[rowg * ODIM + colg] = acc[i][j][r] + b2[colg];
          }
        }
    }
  }
}

// ---------------------------------------------------------------------------
__global__ __launch_bounds__(256) void copy_hfinal_kernel(
    const bf16* __restrict__ Hbf, float* __restrict__ out)
{
  int i = blockIdx.x * blockDim.x + threadIdx.x;
  int b = i / HDIM, n = i % HDIM;
  out[i] = (float)Hbf[((size_t)b * T_STEPS + (T_STEPS - 1)) * HDIM + n];
}

extern "C" void kernel_launch(void* const* d_in, const int* in_sizes, int n_in,
                              void* d_out, int out_size, void* d_ws, size_t ws_size,
                              hipStream_t stream) {
  const float* x  = (const float*)d_in[0];
  const float* W1 = (const float*)d_in[1];
  const float* b1 = (const float*)d_in[2];
  const float* W2 = (const float*)d_in[3];
  const float* b2 = (const float*)d_in[4];

  float* out = (float*)d_out;

  // workspace layout:
  //   [0, 32M)             Hbf
  //   [32M, +512K)         W2b (bf16 of W2, coop path)
  //   [32.5M, +64M)        Aws (fp32 x-projection, coop path — NOT d_out,
  //                        so GEMM3 overlap can't alias unread A rows)
  //   [96.5M, +4K)         progress flags
  bf16*  Hbf   = (bf16*)d_ws;
  size_t HBF_B = (size_t)BATCH * T_STEPS * HDIM * 2;            // 33,554,432
  size_t OFF_W2B = HBF_B;
  size_t OFF_A   = HBF_B + 524288;
  size_t OFF_FLG = OFF_A + (size_t)BATCH * T_STEPS * HDIM * 4;  // +64M
  size_t NEED    = OFF_FLG + 4096;

  bf16*  W2b  = (bf16*)((char*)d_ws + OFF_W2B);
  float* Aws  = (float*)((char*)d_ws + OFF_A);
  int*   prog = (int*)((char*)d_ws + OFF_FLG);

  int smem_dbuf = SMEM_COOP;                       // 163840
  int smem_sbuf = (W_ELEMS + 1 * HB_ELEMS) * 2;    // 147456

  // ---- gate the cooperative path ----------------------------------------
  bool coop_ok = ws_size >= NEED;
  if (coop_ok)
    coop_ok = hipFuncSetAttribute(
                  reinterpret_cast<const void*>(coop_kernel),
                  hipFuncAttributeMaxDynamicSharedMemorySize, SMEM_COOP)
              == hipSuccess;
  if (coop_ok) {
    int mb = 0;
    if (hipOccupancyMaxActiveBlocksPerMultiprocessor(
            &mb, reinterpret_cast<const void*>(coop_kernel), 512,
            (size_t)SMEM_COOP) != hipSuccess)
      mb = 0;
    coop_ok = (mb >= 1);
  }

  if (coop_ok) {
    hipMemsetAsync(prog, 0, 4096, stream);
    conv_f32_bf16_kernel<<<(ODIM * HDIM) / 2048, 256, 0, stream>>>(
        W2, W2b, HDIM, HDIM);
    // GEMM1 (r6 proven) -> Aws, REMAP [T,B,H]
    dim3 g1(BATCH * T_STEPS / 128, HDIM / 128);
    gemm_mfma_kernel<float, true><<<g1, 256, 0, stream>>>(
        x, EDIM, W1, EDIM + HDIM, 0, b1, Aws, HDIM, EDIM);
    // fused scan (4 blocks) + GEMM3 workers (252 blocks), co-resident
    const float* Ac  = Aws;  const float* W1c = W1;  bf16* Hc = Hbf;
    const bf16*  W2c = W2b;  const float* b2c = b2;  float* oc = out;
    int* pc = prog;
    void* kargs[] = {&Ac, &W1c, &Hc, &W2c, &b2c, &oc, &pc};
    hipError_t ce = hipLaunchCooperativeKernel(
        reinterpret_cast<const void*>(coop_kernel), dim3(256), dim3(512),
        kargs, (unsigned)SMEM_COOP, stream);
    if (ce != hipSuccess) {
      // best-effort serial completion (A already in Aws)
      hipFuncSetAttribute(reinterpret_cast<const void*>(scan_kernel<1>),
                          hipFuncAttributeMaxDynamicSharedMemorySize, smem_dbuf);
      scan_kernel<1><<<4, 512, smem_dbuf, stream>>>(Aws, W1, Hbf);
      dim3 g3(BATCH * T_STEPS / 128, ODIM / 128);
      gemm_mfma_kernel<bf16, false><<<g3, 256, 0, stream>>>(
          Hbf, HDIM, W2, HDIM, 0, b2, out, ODIM, HDIM);
    }
  } else {
    // ---- r6 serial path (proven 1375.8 us): A staged in d_out ------------
    float* A = out;
    dim3 g1(BATCH * T_STEPS / 128, HDIM / 128);
    gemm_mfma_kernel<float, true><<<g1, 256, 0, stream>>>(
        x, EDIM, W1, EDIM + HDIM, 0, b1, A, HDIM, EDIM);
    hipError_t e = hipFuncSetAttribute(
        reinterpret_cast<const void*>(scan_kernel<1>),
        hipFuncAttributeMaxDynamicSharedMemorySize, smem_dbuf);
    if (e == hipSuccess) {
      scan_kernel<1><<<4, 512, smem_dbuf, stream>>>(A, W1, Hbf);
    } else {
      hipFuncSetAttribute(reinterpret_cast<const void*>(scan_kernel<0>),
                          hipFuncAttributeMaxDynamicSharedMemorySize, smem_sbuf);
      scan_kernel<0><<<4, 512, smem_sbuf, stream>>>(A, W1, Hbf);
    }
    dim3 g3(BATCH * T_STEPS / 128, ODIM / 128);
    gemm_mfma_kernel<bf16, false><<<g3, 256, 0, stream>>>(
        Hbf, HDIM, W2, HDIM, 0, b2, out, ODIM, HDIM);
  }

  // h_final tail
  copy_hfinal_kernel<<<(BATCH * HDIM) / 256, 256, 0, stream>>>(
      Hbf, out + (size_t)BATCH * T_STEPS * ODIM);
}